// Round 1
// baseline (680.903 us; speedup 1.0000x reference)
//
#include <hip/hip_runtime.h>
#include <hip/hip_cooperative_groups.h>
#include <stdint.h>

namespace cg = cooperative_groups;

#define D 128
#define EPB 4096   // edges per hist/scat block (legacy fallback path)
#define EPB2 1024  // edges per hist/scat block (fused path: more blocks -> better CU coverage)
#define CSZ 128    // nodes per cluster (cluster = dst >> 7)

typedef __bf16 bf16x8 __attribute__((ext_vector_type(8)));
typedef float f32x4 __attribute__((ext_vector_type(4)));

__device__ inline float bf2f(unsigned short u) {
    return __uint_as_float((unsigned)u << 16);
}
__device__ inline unsigned short f2bf(float f) {
    unsigned u = __float_as_uint(f);
    return (unsigned short)((u + 0x7FFF + ((u >> 16) & 1)) >> 16);  // RNE
}

struct Params {
    const float* x; const int* ei; const float* ew;
    const float* W1; const float* b1; const float* W2; const float* b2;
    float* out;
    int N, E, C, B1n, B2n, total, gb, hb, sb;
    unsigned short *Wt1, *Wt2;
    unsigned int* bh; int* ebase; int* bsums;        // legacy scan path
    unsigned int* ctot; int* cbase; unsigned int* gcur; // fused scan path
    float* dinv; int* cnt; int* rowstart;
    int2* brec; int2* erec;
    unsigned short *Hbuf, *Abuf;
};

// ================= phase bodies =================

__device__ inline void dev_prep(int which, const Params& p) {
    const float* W = (which == 0) ? p.W1 : p.W2;
    unsigned short* Wt = (which == 0) ? p.Wt1 : p.Wt2;
    for (int i = threadIdx.x; i < 2048; i += 256) {
        int nn = i >> 4;
        int kc = (i & 15) << 3;
        ushort4 o0, o1;
        o0.x = f2bf(W[(kc + 0) * 128 + nn]); o0.y = f2bf(W[(kc + 1) * 128 + nn]);
        o0.z = f2bf(W[(kc + 2) * 128 + nn]); o0.w = f2bf(W[(kc + 3) * 128 + nn]);
        o1.x = f2bf(W[(kc + 4) * 128 + nn]); o1.y = f2bf(W[(kc + 5) * 128 + nn]);
        o1.z = f2bf(W[(kc + 6) * 128 + nn]); o1.w = f2bf(W[(kc + 7) * 128 + nn]);
        *(ushort4*)(Wt + nn * 128 + kc) = o0;
        *(ushort4*)(Wt + nn * 128 + kc + 4) = o1;
    }
}

// ---- legacy bodies (fallback path) ----
__device__ inline void dev_hist(int b, const Params& p, unsigned int* hist) {
    for (int i = threadIdx.x; i < p.C; i += 256) hist[i] = 0;
    __syncthreads();
    const int base = b * EPB + threadIdx.x;
#pragma unroll
    for (int k = 0; k < EPB / 256; ++k) {
        int e = base + k * 256;
        if (e < p.E) atomicAdd(&hist[((unsigned)p.ei[p.E + e]) >> 7], 1u);
    }
    __syncthreads();
    for (int i = threadIdx.x; i < p.C; i += 256) p.bh[(size_t)b * p.C + i] = hist[i];
}

__device__ inline void dev_scanA(int blk, const Params& p, int* tmp) {
    const int tid = threadIdx.x;
    const int i = blk * 256 + tid;
    int v = 0;
    if (i < p.total) {
        int c = i / p.B1n;
        int b = i - c * p.B1n;
        v = (int)p.bh[(size_t)b * p.C + c];
    }
    tmp[tid] = v;
    __syncthreads();
    for (int off = 1; off < 256; off <<= 1) {
        int t = (tid >= off) ? tmp[tid - off] : 0;
        __syncthreads();
        tmp[tid] += t;
        __syncthreads();
    }
    if (i < p.total) p.ebase[i] = tmp[tid] - v;
    if (tid == 255) p.bsums[blk] = tmp[255];
}

__device__ inline void dev_scanB(int blk, const Params& p, int* sred) {
    const int tid = threadIdx.x;
    int v = (tid < blk) ? p.bsums[tid] : 0;
#pragma unroll
    for (int off = 32; off; off >>= 1) v += __shfl_down(v, off);
    if ((tid & 63) == 0) sred[tid >> 6] = v;
    __syncthreads();
    int tot = sred[0] + sred[1] + sred[2] + sred[3];
    int i = blk * 256 + tid;
    if (i < p.total) p.ebase[i] += tot;
}

__device__ inline void dev_scat(int b, const Params& p, unsigned int* cur) {
    for (int i = threadIdx.x; i < p.C; i += 256) cur[i] = 0;
    __syncthreads();
    const int base = b * EPB + threadIdx.x;
#pragma unroll
    for (int k = 0; k < EPB / 256; ++k) {
        int e = base + k * 256;
        if (e < p.E) {
            int s = p.ei[e];
            unsigned d = (unsigned)p.ei[p.E + e];
            float w = p.ew[e];
            int c = d >> 7;
            unsigned r = atomicAdd(&cur[c], 1u);
            int pos = p.ebase[c * p.B1n + b] + (int)r;
            p.brec[pos] = make_int2((int)((d << 16) | (unsigned)s), __float_as_int(w));
        }
    }
}

// ---- fused-path bodies ----
__device__ inline void dev_hist2(int b, const Params& p, unsigned int* hist) {
    for (int i = threadIdx.x; i < p.C; i += 256) hist[i] = 0;
    __syncthreads();
    const int base = b * EPB2 + threadIdx.x;
#pragma unroll
    for (int k = 0; k < EPB2 / 256; ++k) {
        int e = base + k * 256;
        if (e < p.E) atomicAdd(&hist[((unsigned)p.ei[p.E + e]) >> 7], 1u);
    }
    __syncthreads();
    for (int i = threadIdx.x; i < p.C; i += 256) {
        unsigned v = hist[i];
        if (v) atomicAdd(&p.ctot[i], v);
    }
}

// single-block exclusive scan of ctot[C] (C <= 512) -> cbase, gcur
__device__ inline void dev_cscan(const Params& p, int* s) {
    const int tid = threadIdx.x;
    const int c0 = tid, c1 = tid + 256;
    s[c0] = (c0 < p.C) ? (int)p.ctot[c0] : 0;
    s[c1] = (c1 < p.C) ? (int)p.ctot[c1] : 0;
    __syncthreads();
    for (int off = 1; off < 512; off <<= 1) {
        int t0 = (c0 >= off) ? s[c0 - off] : 0;
        int t1 = (c1 >= off) ? s[c1 - off] : 0;
        __syncthreads();
        s[c0] += t0; s[c1] += t1;
        __syncthreads();
    }
    if (c0 < p.C) { int b0 = (c0 == 0) ? 0 : s[c0 - 1]; p.cbase[c0] = b0; p.gcur[c0] = (unsigned)b0; }
    if (c1 < p.C) { int b1 = s[c1 - 1]; p.cbase[c1] = b1; p.gcur[c1] = (unsigned)b1; }
    if (tid == 0) p.cbase[p.C] = p.E;
}

__device__ inline void dev_scat2(int b, const Params& p, unsigned int* a) {
    unsigned int* hcnt = a;        // [512]
    unsigned int* hcur = a + 512;  // [512]
    const int tid = threadIdx.x;
    for (int i = tid; i < p.C; i += 256) hcnt[i] = 0;
    __syncthreads();
    const int base = b * EPB2 + tid;
#pragma unroll
    for (int k = 0; k < EPB2 / 256; ++k) {
        int e = base + k * 256;
        if (e < p.E) atomicAdd(&hcnt[((unsigned)p.ei[p.E + e]) >> 7], 1u);
    }
    __syncthreads();
    for (int i = tid; i < p.C; i += 256) {
        unsigned c = hcnt[i];
        hcur[i] = c ? atomicAdd(&p.gcur[i], c) : 0u;  // reserve contiguous chunk in cluster segment
    }
    __syncthreads();
#pragma unroll
    for (int k = 0; k < EPB2 / 256; ++k) {
        int e = base + k * 256;
        if (e < p.E) {
            int s = p.ei[e];
            unsigned d = (unsigned)p.ei[p.E + e];
            float w = p.ew[e];
            int c = (int)(d >> 7);
            unsigned r = atomicAdd(&hcur[c], 1u);
            p.brec[r] = make_int2((int)((d << 16) | (unsigned)s), __float_as_int(w));
        }
    }
}

// cbuild with explicit cluster segment [cs, ce)
__device__ inline void dev_cbuild(int c, const Params& p, unsigned int* a, int cs, int ce) {
    unsigned int* hcnt = a;
    unsigned int* hdeg = a + CSZ;
    unsigned int* lsc  = a + 2 * CSZ;
    unsigned int* curs = a + 3 * CSZ;
    const int tid = threadIdx.x;
    if (tid < CSZ) { hcnt[tid] = 0; hdeg[tid] = 0; }
    __syncthreads();
    for (int i = cs + tid; i < ce; i += 256) {
        int2 r = p.brec[i];
        int local = (int)(((unsigned)r.x) >> 16) & (CSZ - 1);
        atomicAdd(&hcnt[local], 1u);
        atomicAdd(&hdeg[local], (unsigned)(__int_as_float(r.y) * 16777216.0f));
    }
    __syncthreads();
    if (tid < CSZ) lsc[tid] = hcnt[tid];
    __syncthreads();
    for (int off = 1; off < CSZ; off <<= 1) {
        unsigned t = (tid < CSZ && tid >= off) ? lsc[tid - off] : 0u;
        __syncthreads();
        if (tid < CSZ) lsc[tid] += t;
        __syncthreads();
    }
    if (tid < CSZ) {
        unsigned excl = lsc[tid] - hcnt[tid];
        curs[tid] = excl;
        int node = c * CSZ + tid;
        if (node < p.N) {
            p.rowstart[node] = cs + (int)excl;
            p.cnt[node] = (int)hcnt[tid];
            float deg = 1.0f + (float)hdeg[tid] * (1.0f / 16777216.0f);
            p.dinv[node] = rsqrtf(deg);
        }
    }
    __syncthreads();
    for (int i = cs + tid; i < ce; i += 256) {
        int2 r = p.brec[i];
        int local = (int)(((unsigned)r.x) >> 16) & (CSZ - 1);
        unsigned rk = atomicAdd(&curs[local], 1u);
        p.erec[cs + (int)rk] = make_int2(r.x & 0xFFFF, r.y);   // (src, ew)
    }
}

// ---------------- MFMA GEMM body (R6-verified): direct-global A/B frags ----------------
template <bool IN_BF16>
__device__ inline void mfma_body(unsigned short* sE,
                                 const void* __restrict__ Xv,
                                 const unsigned short* __restrict__ Wt,
                                 unsigned short* __restrict__ H, int n, int blk) {
    const int tid = threadIdx.x;
    const int row0 = blk * 64;
    const int lane = tid & 63;
    const int wv = tid >> 6;
    const int qm = lane & 15;
    const int quad = lane >> 4;

    const int arow = row0 + wv * 16 + qm;
    const int ar = (arow < n) ? arow : (n - 1);

    f32x4 acc[8];
#pragma unroll
    for (int i = 0; i < 8; ++i) acc[i] = (f32x4){0.f, 0.f, 0.f, 0.f};

#pragma unroll
    for (int kb = 0; kb < 4; ++kb) {
        const int koff = kb * 32 + quad * 8;
        bf16x8 a;
        if (IN_BF16) {
            a = *(const bf16x8*)((const unsigned short*)Xv + (size_t)ar * 128 + koff);
        } else {
            const float* Xf = (const float*)Xv + (size_t)ar * 128 + koff;
            float4 v0 = *(const float4*)(Xf);
            float4 v1 = *(const float4*)(Xf + 4);
            union { bf16x8 v; ushort4 u[2]; } cv;
            cv.u[0].x = f2bf(v0.x); cv.u[0].y = f2bf(v0.y);
            cv.u[0].z = f2bf(v0.z); cv.u[0].w = f2bf(v0.w);
            cv.u[1].x = f2bf(v1.x); cv.u[1].y = f2bf(v1.y);
            cv.u[1].z = f2bf(v1.z); cv.u[1].w = f2bf(v1.w);
            a = cv.v;
        }
#pragma unroll
        for (int n0 = 0; n0 < 8; ++n0) {
            bf16x8 b = *(const bf16x8*)(Wt + (n0 * 16 + qm) * 128 + koff);
            acc[n0] = __builtin_amdgcn_mfma_f32_16x16x32_bf16(a, b, acc[n0], 0, 0, 0);
        }
    }

#pragma unroll
    for (int n0 = 0; n0 < 8; ++n0)
#pragma unroll
        for (int r = 0; r < 4; ++r)
            sE[(wv * 16 + quad * 4 + r) * 136 + n0 * 16 + qm] = f2bf(acc[n0][r]);
    __syncthreads();

    const int row_in = lane >> 2;
    const int c0 = (lane & 3) * 4;
    const int grow = row0 + wv * 16 + row_in;
    if (grow < n) {
#pragma unroll
        for (int j = 0; j < 4; ++j)
            *(int4*)(H + (size_t)grow * 128 + (c0 + j) * 8) =
                *(const int4*)(&sE[(wv * 16 + row_in) * 136 + (c0 + j) * 8]);
    }
}

// ---------------- gather body: OUT[d] = b + dinv[d]*(dinv[d]*H[d] + sum (dinv[s]*ew)*H[s]) ----------------
// NOTE: no early `return` — safe inside the fused cooperative kernel (grid.sync follows).
template <bool OUT_BF16>
__device__ inline void gather_body(const Params& p, const ushort4* __restrict__ H4,
                                   const float4* __restrict__ bias4,
                                   void* __restrict__ OUTv, int g) {
    const int lane = threadIdx.x & 31;
    const int node = g * 8 + (threadIdx.x >> 5);
    if (node < p.N) {
        const int start = p.rowstart[node];
        const int m = p.cnt[node];
        const float di = p.dinv[node];

        float4 b = bias4[lane];
        ushort4 h = H4[(size_t)node * 32 + lane];
        float ax = di * bf2f(h.x);
        float ay = di * bf2f(h.y);
        float az = di * bf2f(h.z);
        float aw = di * bf2f(h.w);

        int j = 0;
        for (; j + 4 <= m; j += 4) {
            const int base = start + j;
            int2 e0 = p.erec[base + 0], e1 = p.erec[base + 1];
            int2 e2 = p.erec[base + 2], e3 = p.erec[base + 3];
            float w0 = p.dinv[e0.x] * __int_as_float(e0.y);
            float w1 = p.dinv[e1.x] * __int_as_float(e1.y);
            float w2 = p.dinv[e2.x] * __int_as_float(e2.y);
            float w3 = p.dinv[e3.x] * __int_as_float(e3.y);
            ushort4 v0 = H4[(size_t)e0.x * 32 + lane];
            ushort4 v1 = H4[(size_t)e1.x * 32 + lane];
            ushort4 v2 = H4[(size_t)e2.x * 32 + lane];
            ushort4 v3 = H4[(size_t)e3.x * 32 + lane];
            ax += w0 * bf2f(v0.x); ay += w0 * bf2f(v0.y); az += w0 * bf2f(v0.z); aw += w0 * bf2f(v0.w);
            ax += w1 * bf2f(v1.x); ay += w1 * bf2f(v1.y); az += w1 * bf2f(v1.z); aw += w1 * bf2f(v1.w);
            ax += w2 * bf2f(v2.x); ay += w2 * bf2f(v2.y); az += w2 * bf2f(v2.z); aw += w2 * bf2f(v2.w);
            ax += w3 * bf2f(v3.x); ay += w3 * bf2f(v3.y); az += w3 * bf2f(v3.z); aw += w3 * bf2f(v3.w);
        }
        for (; j < m; ++j) {
            int2 er = p.erec[start + j];
            float w = p.dinv[er.x] * __int_as_float(er.y);
            ushort4 v = H4[(size_t)er.x * 32 + lane];
            ax += w * bf2f(v.x); ay += w * bf2f(v.y); az += w * bf2f(v.z); aw += w * bf2f(v.w);
        }
        ax = b.x + di * ax; ay = b.y + di * ay;
        az = b.z + di * az; aw = b.w + di * aw;
        if (OUT_BF16) {
            ushort4 o;
            o.x = f2bf(fmaxf(ax, 0.f)); o.y = f2bf(fmaxf(ay, 0.f));
            o.z = f2bf(fmaxf(az, 0.f)); o.w = f2bf(fmaxf(aw, 0.f));
            ((ushort4*)OUTv)[(size_t)node * 32 + lane] = o;
        } else {
            float4 o; o.x = ax; o.y = ay; o.z = az; o.w = aw;
            ((float4*)OUTv)[(size_t)node * 32 + lane] = o;
        }
    }
}

// ================= fused cooperative kernel =================
// 7 phases, 6 grid syncs. Grid must be fully co-resident (launch via hipLaunchCooperativeKernel,
// grid <= occupancy * numCU, guaranteed by __launch_bounds__(256,4): <=128 VGPR, 17.4KB LDS).
__global__ __launch_bounds__(256, 4) void k_all(Params p) {
    __shared__ __align__(16) char arena[64 * 136 * 2];
    cg::grid_group grid = cg::this_grid();
    const int nb = (int)gridDim.x;

    // P0: weight transpose (2 units) + cluster histogram -> global totals (B2n units)
    for (int u = blockIdx.x; u < 2 + p.B2n; u += nb) {
        if (u < 2) dev_prep(u, p);
        else dev_hist2(u - 2, p, (unsigned int*)arena);
        __syncthreads();
    }
    grid.sync();

    // P1: GEMM1 (x @ W1 -> Hbuf, bf16) + single-block cluster scan
    for (int u = blockIdx.x; u < p.gb + 1; u += nb) {
        if (u < p.gb) mfma_body<false>((unsigned short*)arena, (const void*)p.x, p.Wt1, p.Hbuf, p.N, u);
        else dev_cscan(p, (int*)arena);
        __syncthreads();
    }
    grid.sync();

    // P2: scatter edges into cluster-sorted brec via chunk reservation
    for (int u = blockIdx.x; u < p.B2n; u += nb) {
        dev_scat2(u, p, (unsigned int*)arena);
        __syncthreads();
    }
    grid.sync();

    // P3: per-cluster CSR build (rowstart/cnt/dinv/erec)
    for (int u = blockIdx.x; u < p.C; u += nb) {
        dev_cbuild(u, p, (unsigned int*)arena, p.cbase[u], p.cbase[u + 1]);
        __syncthreads();
    }
    grid.sync();

    // P4: gather layer 1 (+bias, ReLU) -> Abuf bf16
    for (int u = blockIdx.x; u < p.hb; u += nb)
        gather_body<true>(p, (const ushort4*)p.Hbuf, (const float4*)p.b1, (void*)p.Abuf, u);
    grid.sync();

    // P5: GEMM2 (Abuf @ W2 -> Hbuf, bf16)
    for (int u = blockIdx.x; u < p.gb; u += nb) {
        mfma_body<true>((unsigned short*)arena, (const void*)p.Abuf, p.Wt2, p.Hbuf, p.N, u);
        __syncthreads();
    }
    grid.sync();

    // P6: gather layer 2 (+bias) -> out fp32
    for (int u = blockIdx.x; u < p.hb; u += nb)
        gather_body<false>(p, (const ushort4*)p.Hbuf, (const float4*)p.b2, (void*)p.out, u);
}

// ================= legacy 8-kernel pipeline (fallback) =================
__global__ __launch_bounds__(256, 4) void k_f0(Params p) {
    __shared__ __align__(16) char arena[64 * 136 * 2];
    if (blockIdx.x < 2) dev_prep(blockIdx.x, p);
    else dev_hist(blockIdx.x - 2, p, (unsigned int*)arena);
}
__global__ __launch_bounds__(256, 4) void k_f1(Params p) {
    __shared__ __align__(16) char arena[64 * 136 * 2];
    if ((int)blockIdx.x < p.gb) mfma_body<false>((unsigned short*)arena, (const void*)p.x, p.Wt1, p.Hbuf, p.N, blockIdx.x);
    else dev_scanA(blockIdx.x - p.gb, p, (int*)arena);
}
__global__ __launch_bounds__(256) void k_f2(Params p) {
    __shared__ int sred[4];
    dev_scanB(blockIdx.x, p, sred);
}
__global__ __launch_bounds__(256) void k_f3(Params p) {
    __shared__ unsigned int cur[512];
    dev_scat(blockIdx.x, p, cur);
}
__global__ __launch_bounds__(256) void k_f4(Params p) {
    __shared__ unsigned int a[4 * CSZ];
    int c = blockIdx.x;
    int cs = p.ebase[c * p.B1n];
    int ce = (c + 1 < p.C) ? p.ebase[(c + 1) * p.B1n] : p.E;
    dev_cbuild(c, p, a, cs, ce);
}
__global__ __launch_bounds__(256) void k_f5(Params p) {
    gather_body<true>(p, (const ushort4*)p.Hbuf, (const float4*)p.b1, (void*)p.Abuf, blockIdx.x);
}
__global__ __launch_bounds__(256, 4) void k_f6(Params p) {
    __shared__ __align__(16) char arena[64 * 136 * 2];
    mfma_body<true>((unsigned short*)arena, (const void*)p.Abuf, p.Wt2, p.Hbuf, p.N, blockIdx.x);
}
__global__ __launch_bounds__(256) void k_f7(Params p) {
    gather_body<false>(p, (const ushort4*)p.Hbuf, (const float4*)p.b2, (void*)p.out, blockIdx.x);
}

extern "C" void kernel_launch(void* const* d_in, const int* in_sizes, int n_in,
                              void* d_out, int out_size, void* d_ws, size_t ws_size,
                              hipStream_t stream) {
    Params p;
    p.x  = (const float*)d_in[0];
    p.ei = (const int*)d_in[1];
    p.ew = (const float*)d_in[2];
    p.W1 = (const float*)d_in[3];
    p.b1 = (const float*)d_in[4];
    p.W2 = (const float*)d_in[5];
    p.b2 = (const float*)d_in[6];
    p.out = (float*)d_out;

    p.N = in_sizes[0] / D;
    p.E = in_sizes[2];
    p.C = (p.N + CSZ - 1) / CSZ;
    p.B1n = (p.E + EPB - 1) / EPB;
    p.B2n = (p.E + EPB2 - 1) / EPB2;
    p.total = p.C * p.B1n;
    p.sb = (p.total + 255) / 256;
    p.gb = (p.N + 63) / 64;
    p.hb = (p.N + 7) / 8;

    char* w = (char*)d_ws;
    auto alloc = [&](size_t bytes) {
        void* r = (void*)w;
        w += (bytes + 255) & ~(size_t)255;
        return r;
    };
    p.bh       = (unsigned int*)alloc((size_t)p.total * 4);
    p.ebase    = (int*)alloc((size_t)p.total * 4);
    p.bsums    = (int*)alloc(1024 * 4);
    p.ctot     = (unsigned int*)alloc((size_t)p.C * 4);
    p.cbase    = (int*)alloc((size_t)(p.C + 1) * 4);
    p.gcur     = (unsigned int*)alloc((size_t)p.C * 4);
    p.dinv     = (float*)alloc((size_t)p.N * 4);
    p.cnt      = (int*)alloc((size_t)p.N * 4);
    p.rowstart = (int*)alloc((size_t)p.N * 4);
    p.brec     = (int2*)alloc((size_t)p.E * 8);
    p.erec     = (int2*)alloc((size_t)p.E * 8);
    p.Hbuf     = (unsigned short*)alloc((size_t)p.N * D * 2);
    p.Abuf     = (unsigned short*)alloc((size_t)p.N * D * 2);
    p.Wt1      = (unsigned short*)alloc(128 * 128 * 2);
    p.Wt2      = (unsigned short*)alloc(128 * 128 * 2);

    // fused path needs C <= 512 (single-block cluster scan); true for N=50000 (C=391)
    bool fused_ok = (p.C <= 512);

    static int s_grid = 0;
    if (s_grid == 0) {
        int ba = 0;
        if (hipOccupancyMaxActiveBlocksPerMultiprocessor(&ba, (const void*)k_all, 256, 0) != hipSuccess || ba < 1)
            ba = 2;  // conservative: co-residency still guaranteed
        int ncu = 256;
        hipDeviceProp_t prop;
        int dev = 0;
        if (hipGetDevice(&dev) == hipSuccess && hipGetDeviceProperties(&prop, dev) == hipSuccess &&
            prop.multiProcessorCount > 0)
            ncu = prop.multiProcessorCount;
        long g = (long)ba * (long)ncu;
        s_grid = (int)(g > 1024 ? 1024 : g);
        if (s_grid < 64) s_grid = 64;
    }

    hipError_t err = hipErrorUnknown;
    if (fused_ok) {
        hipMemsetAsync(p.ctot, 0, (size_t)p.C * 4, stream);
        void* kargs[] = { (void*)&p };
        err = hipLaunchCooperativeKernel((const void*)k_all, dim3(s_grid), dim3(256), kargs, 0u, stream);
    }
    if (err != hipSuccess) {
        // fallback: original 8-kernel pipeline
        k_f0<<<2 + p.B1n, 256, 0, stream>>>(p);
        k_f1<<<p.gb + p.sb, 256, 0, stream>>>(p);
        k_f2<<<p.sb, 256, 0, stream>>>(p);
        k_f3<<<p.B1n, 256, 0, stream>>>(p);
        k_f4<<<p.C, 256, 0, stream>>>(p);
        k_f5<<<p.hb, 256, 0, stream>>>(p);
        k_f6<<<p.gb, 256, 0, stream>>>(p);
        k_f7<<<p.hb, 256, 0, stream>>>(p);
    }
}

// Round 2
// 227.494 us; speedup vs baseline: 2.9931x; 2.9931x over previous
//
#include <hip/hip_runtime.h>
#include <stdint.h>

#define D 128
#define EPB2 1024  // edges per hist/scat block
#define CSZ 128    // nodes per cluster (cluster = dst >> 7)

typedef __bf16 bf16x8 __attribute__((ext_vector_type(8)));
typedef float f32x4 __attribute__((ext_vector_type(4)));

__device__ inline float bf2f(unsigned short u) {
    return __uint_as_float((unsigned)u << 16);
}
__device__ inline unsigned short f2bf(float f) {
    unsigned u = __float_as_uint(f);
    return (unsigned short)((u + 0x7FFF + ((u >> 16) & 1)) >> 16);  // RNE
}

struct Params {
    const float* x; const int* ei; const float* ew;
    const float* W1; const float* b1; const float* W2; const float* b2;
    float* out;
    int N, E, C, B2n, gb, hb;
    unsigned short *Wt1, *Wt2;
    unsigned int* ctot; int* cbase; unsigned int* gcur;
    float* dinv; int* cnt; int* rowstart;
    int2* brec; int2* erec;
    unsigned short *Hbuf, *H2;
};

// ================= phase bodies =================

__device__ inline void dev_prep(int which, const Params& p) {
    const float* W = (which == 0) ? p.W1 : p.W2;
    unsigned short* Wt = (which == 0) ? p.Wt1 : p.Wt2;
    for (int i = threadIdx.x; i < 2048; i += 256) {
        int nn = i >> 4;
        int kc = (i & 15) << 3;
        ushort4 o0, o1;
        o0.x = f2bf(W[(kc + 0) * 128 + nn]); o0.y = f2bf(W[(kc + 1) * 128 + nn]);
        o0.z = f2bf(W[(kc + 2) * 128 + nn]); o0.w = f2bf(W[(kc + 3) * 128 + nn]);
        o1.x = f2bf(W[(kc + 4) * 128 + nn]); o1.y = f2bf(W[(kc + 5) * 128 + nn]);
        o1.z = f2bf(W[(kc + 6) * 128 + nn]); o1.w = f2bf(W[(kc + 7) * 128 + nn]);
        *(ushort4*)(Wt + nn * 128 + kc) = o0;
        *(ushort4*)(Wt + nn * 128 + kc + 4) = o1;
    }
}

// per-block LDS cluster histogram -> global totals (atomics). Validated in R1.
__device__ inline void dev_hist2(int b, const Params& p, unsigned int* hist) {
    for (int i = threadIdx.x; i < p.C; i += 256) hist[i] = 0;
    __syncthreads();
    const int base = b * EPB2 + threadIdx.x;
#pragma unroll
    for (int k = 0; k < EPB2 / 256; ++k) {
        int e = base + k * 256;
        if (e < p.E) atomicAdd(&hist[((unsigned)p.ei[p.E + e]) >> 7], 1u);
    }
    __syncthreads();
    for (int i = threadIdx.x; i < p.C; i += 256) {
        unsigned v = hist[i];
        if (v) atomicAdd(&p.ctot[i], v);
    }
}

// single-block exclusive scan of ctot[C] (C <= 512) -> cbase, gcur. Validated in R1.
__device__ inline void dev_cscan(const Params& p, int* s) {
    const int tid = threadIdx.x;
    const int c0 = tid, c1 = tid + 256;
    s[c0] = (c0 < p.C) ? (int)p.ctot[c0] : 0;
    s[c1] = (c1 < p.C) ? (int)p.ctot[c1] : 0;
    __syncthreads();
    for (int off = 1; off < 512; off <<= 1) {
        int t0 = (c0 >= off) ? s[c0 - off] : 0;
        int t1 = (c1 >= off) ? s[c1 - off] : 0;
        __syncthreads();
        s[c0] += t0; s[c1] += t1;
        __syncthreads();
    }
    if (c0 < p.C) { int b0 = (c0 == 0) ? 0 : s[c0 - 1]; p.cbase[c0] = b0; p.gcur[c0] = (unsigned)b0; }
    if (c1 < p.C) { int b1 = s[c1 - 1]; p.cbase[c1] = b1; p.gcur[c1] = (unsigned)b1; }
    if (tid == 0) p.cbase[p.C] = p.E;
}

// scatter edges into cluster-sorted brec via per-cluster chunk reservation. Validated in R1.
__device__ inline void dev_scat2(int b, const Params& p, unsigned int* a) {
    unsigned int* hcnt = a;        // [512]
    unsigned int* hcur = a + 512;  // [512]
    const int tid = threadIdx.x;
    for (int i = tid; i < p.C; i += 256) hcnt[i] = 0;
    __syncthreads();
    const int base = b * EPB2 + tid;
#pragma unroll
    for (int k = 0; k < EPB2 / 256; ++k) {
        int e = base + k * 256;
        if (e < p.E) atomicAdd(&hcnt[((unsigned)p.ei[p.E + e]) >> 7], 1u);
    }
    __syncthreads();
    for (int i = tid; i < p.C; i += 256) {
        unsigned c = hcnt[i];
        hcur[i] = c ? atomicAdd(&p.gcur[i], c) : 0u;
    }
    __syncthreads();
#pragma unroll
    for (int k = 0; k < EPB2 / 256; ++k) {
        int e = base + k * 256;
        if (e < p.E) {
            int s = p.ei[e];
            unsigned d = (unsigned)p.ei[p.E + e];
            float w = p.ew[e];
            int c = (int)(d >> 7);
            unsigned r = atomicAdd(&hcur[c], 1u);
            p.brec[r] = make_int2((int)((d << 16) | (unsigned)s), __float_as_int(w));
        }
    }
}

// per-cluster CSR build with explicit segment [cs, ce)
__device__ inline void dev_cbuild(int c, const Params& p, unsigned int* a, int cs, int ce) {
    unsigned int* hcnt = a;
    unsigned int* hdeg = a + CSZ;
    unsigned int* lsc  = a + 2 * CSZ;
    unsigned int* curs = a + 3 * CSZ;
    const int tid = threadIdx.x;
    if (tid < CSZ) { hcnt[tid] = 0; hdeg[tid] = 0; }
    __syncthreads();
    for (int i = cs + tid; i < ce; i += 256) {
        int2 r = p.brec[i];
        int local = (int)(((unsigned)r.x) >> 16) & (CSZ - 1);
        atomicAdd(&hcnt[local], 1u);
        atomicAdd(&hdeg[local], (unsigned)(__int_as_float(r.y) * 16777216.0f));
    }
    __syncthreads();
    if (tid < CSZ) lsc[tid] = hcnt[tid];
    __syncthreads();
    for (int off = 1; off < CSZ; off <<= 1) {
        unsigned t = (tid < CSZ && tid >= off) ? lsc[tid - off] : 0u;
        __syncthreads();
        if (tid < CSZ) lsc[tid] += t;
        __syncthreads();
    }
    if (tid < CSZ) {
        unsigned excl = lsc[tid] - hcnt[tid];
        curs[tid] = excl;
        int node = c * CSZ + tid;
        if (node < p.N) {
            p.rowstart[node] = cs + (int)excl;
            p.cnt[node] = (int)hcnt[tid];
            float deg = 1.0f + (float)hdeg[tid] * (1.0f / 16777216.0f);
            p.dinv[node] = rsqrtf(deg);
        }
    }
    __syncthreads();
    for (int i = cs + tid; i < ce; i += 256) {
        int2 r = p.brec[i];
        int local = (int)(((unsigned)r.x) >> 16) & (CSZ - 1);
        unsigned rk = atomicAdd(&curs[local], 1u);
        p.erec[cs + (int)rk] = make_int2(r.x & 0xFFFF, r.y);   // (src, ew)
    }
}

// ---------------- MFMA GEMM body (R6-verified): direct-global A, B frags ----------------
template <bool IN_BF16>
__device__ inline void mfma_body(unsigned short* sE,
                                 const void* __restrict__ Xv,
                                 const unsigned short* __restrict__ Wt,
                                 unsigned short* __restrict__ H, int n, int blk) {
    const int tid = threadIdx.x;
    const int row0 = blk * 64;
    const int lane = tid & 63;
    const int wv = tid >> 6;
    const int qm = lane & 15;
    const int quad = lane >> 4;

    const int arow = row0 + wv * 16 + qm;
    const int ar = (arow < n) ? arow : (n - 1);

    f32x4 acc[8];
#pragma unroll
    for (int i = 0; i < 8; ++i) acc[i] = (f32x4){0.f, 0.f, 0.f, 0.f};

#pragma unroll
    for (int kb = 0; kb < 4; ++kb) {
        const int koff = kb * 32 + quad * 8;
        bf16x8 a;
        if (IN_BF16) {
            a = *(const bf16x8*)((const unsigned short*)Xv + (size_t)ar * 128 + koff);
        } else {
            const float* Xf = (const float*)Xv + (size_t)ar * 128 + koff;
            float4 v0 = *(const float4*)(Xf);
            float4 v1 = *(const float4*)(Xf + 4);
            union { bf16x8 v; ushort4 u[2]; } cv;
            cv.u[0].x = f2bf(v0.x); cv.u[0].y = f2bf(v0.y);
            cv.u[0].z = f2bf(v0.z); cv.u[0].w = f2bf(v0.w);
            cv.u[1].x = f2bf(v1.x); cv.u[1].y = f2bf(v1.y);
            cv.u[1].z = f2bf(v1.z); cv.u[1].w = f2bf(v1.w);
            a = cv.v;
        }
#pragma unroll
        for (int n0 = 0; n0 < 8; ++n0) {
            bf16x8 b = *(const bf16x8*)(Wt + (n0 * 16 + qm) * 128 + koff);
            acc[n0] = __builtin_amdgcn_mfma_f32_16x16x32_bf16(a, b, acc[n0], 0, 0, 0);
        }
    }

#pragma unroll
    for (int n0 = 0; n0 < 8; ++n0)
#pragma unroll
        for (int r = 0; r < 4; ++r)
            sE[(wv * 16 + quad * 4 + r) * 136 + n0 * 16 + qm] = f2bf(acc[n0][r]);
    __syncthreads();

    const int row_in = lane >> 2;
    const int c0 = (lane & 3) * 4;
    const int grow = row0 + wv * 16 + row_in;
    if (grow < n) {
#pragma unroll
        for (int j = 0; j < 4; ++j)
            *(int4*)(H + (size_t)grow * 128 + (c0 + j) * 8) =
                *(const int4*)(&sE[(wv * 16 + row_in) * 136 + (c0 + j) * 8]);
    }
}

// ---------------- gather layer-1 into LDS (64 rows, bf16, bias+ReLU applied) ----------------
// 8 lanes per node (16 cols each), 32 nodes per pass, 2 passes.
__device__ inline void gather1_to_lds(const Params& p, unsigned short* sA, int row0) {
    const int tid = threadIdx.x;
    const int lane8 = tid & 7;
    const int grp = tid >> 3;  // 0..31
    const ushort4* __restrict__ H4 = (const ushort4*)p.Hbuf;
#pragma unroll
    for (int pass = 0; pass < 2; ++pass) {
        const int local = pass * 32 + grp;
        const int node = row0 + local;
        unsigned short* dst = sA + local * 136 + lane8 * 16;
        if (node < p.N) {
            const int start = p.rowstart[node];
            const int m = p.cnt[node];
            const float di = p.dinv[node];
            const ushort4* Hrow = H4 + (size_t)node * 32 + lane8 * 4;
            float acc[16];
#pragma unroll
            for (int q = 0; q < 4; ++q) {
                ushort4 h = Hrow[q];
                acc[q * 4 + 0] = di * bf2f(h.x);
                acc[q * 4 + 1] = di * bf2f(h.y);
                acc[q * 4 + 2] = di * bf2f(h.z);
                acc[q * 4 + 3] = di * bf2f(h.w);
            }
            int j = 0;
            for (; j + 2 <= m; j += 2) {
                int2 e0 = p.erec[start + j];
                int2 e1 = p.erec[start + j + 1];
                float w0 = p.dinv[e0.x] * __int_as_float(e0.y);
                float w1 = p.dinv[e1.x] * __int_as_float(e1.y);
                const ushort4* V0 = H4 + (size_t)e0.x * 32 + lane8 * 4;
                const ushort4* V1 = H4 + (size_t)e1.x * 32 + lane8 * 4;
#pragma unroll
                for (int q = 0; q < 4; ++q) {
                    ushort4 v0 = V0[q], v1 = V1[q];
                    acc[q * 4 + 0] += w0 * bf2f(v0.x) + w1 * bf2f(v1.x);
                    acc[q * 4 + 1] += w0 * bf2f(v0.y) + w1 * bf2f(v1.y);
                    acc[q * 4 + 2] += w0 * bf2f(v0.z) + w1 * bf2f(v1.z);
                    acc[q * 4 + 3] += w0 * bf2f(v0.w) + w1 * bf2f(v1.w);
                }
            }
            if (j < m) {
                int2 e0 = p.erec[start + j];
                float w0 = p.dinv[e0.x] * __int_as_float(e0.y);
                const ushort4* V0 = H4 + (size_t)e0.x * 32 + lane8 * 4;
#pragma unroll
                for (int q = 0; q < 4; ++q) {
                    ushort4 v0 = V0[q];
                    acc[q * 4 + 0] += w0 * bf2f(v0.x);
                    acc[q * 4 + 1] += w0 * bf2f(v0.y);
                    acc[q * 4 + 2] += w0 * bf2f(v0.z);
                    acc[q * 4 + 3] += w0 * bf2f(v0.w);
                }
            }
            const float* bb = p.b1 + lane8 * 16;
#pragma unroll
            for (int q = 0; q < 4; ++q) {
                ushort4 o;
                o.x = f2bf(fmaxf(bb[q * 4 + 0] + di * acc[q * 4 + 0], 0.f));
                o.y = f2bf(fmaxf(bb[q * 4 + 1] + di * acc[q * 4 + 1], 0.f));
                o.z = f2bf(fmaxf(bb[q * 4 + 2] + di * acc[q * 4 + 2], 0.f));
                o.w = f2bf(fmaxf(bb[q * 4 + 3] + di * acc[q * 4 + 3], 0.f));
                *(ushort4*)(dst + q * 4) = o;
            }
        } else {
            ushort4 z = {0, 0, 0, 0};
#pragma unroll
            for (int q = 0; q < 4; ++q) *(ushort4*)(dst + q * 4) = z;
        }
    }
}

// ---------------- gather body (layer 2): OUT = b + dinv*(dinv*H + sum w*H[src]), fp32 out ----------------
__device__ inline void gather2_body(const Params& p, const ushort4* __restrict__ H4,
                                    const float4* __restrict__ bias4,
                                    float4* __restrict__ OUT, int g) {
    const int lane = threadIdx.x & 31;
    const int node = g * 8 + (threadIdx.x >> 5);
    if (node >= p.N) return;
    const int start = p.rowstart[node];
    const int m = p.cnt[node];
    const float di = p.dinv[node];

    float4 b = bias4[lane];
    ushort4 h = H4[(size_t)node * 32 + lane];
    float ax = di * bf2f(h.x);
    float ay = di * bf2f(h.y);
    float az = di * bf2f(h.z);
    float aw = di * bf2f(h.w);

    int j = 0;
    for (; j + 4 <= m; j += 4) {
        const int base = start + j;
        int2 e0 = p.erec[base + 0], e1 = p.erec[base + 1];
        int2 e2 = p.erec[base + 2], e3 = p.erec[base + 3];
        float w0 = p.dinv[e0.x] * __int_as_float(e0.y);
        float w1 = p.dinv[e1.x] * __int_as_float(e1.y);
        float w2 = p.dinv[e2.x] * __int_as_float(e2.y);
        float w3 = p.dinv[e3.x] * __int_as_float(e3.y);
        ushort4 v0 = H4[(size_t)e0.x * 32 + lane];
        ushort4 v1 = H4[(size_t)e1.x * 32 + lane];
        ushort4 v2 = H4[(size_t)e2.x * 32 + lane];
        ushort4 v3 = H4[(size_t)e3.x * 32 + lane];
        ax += w0 * bf2f(v0.x); ay += w0 * bf2f(v0.y); az += w0 * bf2f(v0.z); aw += w0 * bf2f(v0.w);
        ax += w1 * bf2f(v1.x); ay += w1 * bf2f(v1.y); az += w1 * bf2f(v1.z); aw += w1 * bf2f(v1.w);
        ax += w2 * bf2f(v2.x); ay += w2 * bf2f(v2.y); az += w2 * bf2f(v2.z); aw += w2 * bf2f(v2.w);
        ax += w3 * bf2f(v3.x); ay += w3 * bf2f(v3.y); az += w3 * bf2f(v3.z); aw += w3 * bf2f(v3.w);
    }
    for (; j < m; ++j) {
        int2 er = p.erec[start + j];
        float w = p.dinv[er.x] * __int_as_float(er.y);
        ushort4 v = H4[(size_t)er.x * 32 + lane];
        ax += w * bf2f(v.x); ay += w * bf2f(v.y); az += w * bf2f(v.z); aw += w * bf2f(v.w);
    }
    float4 o;
    o.x = b.x + di * ax; o.y = b.y + di * ay;
    o.z = b.z + di * az; o.w = b.w + di * aw;
    OUT[(size_t)node * 32 + lane] = o;
}

// ================= 6-kernel pipeline =================
__global__ __launch_bounds__(256, 4) void k_a0(Params p) {   // prep + hist
    __shared__ __align__(16) unsigned int hist[512];
    if (blockIdx.x < 2) dev_prep(blockIdx.x, p);
    else dev_hist2(blockIdx.x - 2, p, hist);
}
__global__ __launch_bounds__(256, 4) void k_a1(Params p) {   // GEMM1 + cluster scan
    __shared__ __align__(16) char arena[64 * 136 * 2];
    if ((int)blockIdx.x < p.gb) mfma_body<false>((unsigned short*)arena, (const void*)p.x, p.Wt1, p.Hbuf, p.N, blockIdx.x);
    else dev_cscan(p, (int*)arena);
}
__global__ __launch_bounds__(256) void k_a2(Params p) {      // scatter
    __shared__ unsigned int a[1024];
    dev_scat2(blockIdx.x, p, a);
}
__global__ __launch_bounds__(256) void k_a3(Params p) {      // CSR build
    __shared__ unsigned int a[4 * CSZ];
    dev_cbuild(blockIdx.x, p, a, p.cbase[blockIdx.x], p.cbase[blockIdx.x + 1]);
}
__global__ __launch_bounds__(256, 4) void k_a4(Params p) {   // fused gather1 + GEMM2
    __shared__ __align__(16) unsigned short sA[64 * 136];
    __shared__ __align__(16) unsigned short sE[64 * 136];
    const int row0 = blockIdx.x * 64;
    gather1_to_lds(p, sA, row0);
    __syncthreads();

    const int tid = threadIdx.x;
    const int lane = tid & 63;
    const int wv = tid >> 6;
    const int qm = lane & 15;
    const int quad = lane >> 4;

    f32x4 acc[8];
#pragma unroll
    for (int i = 0; i < 8; ++i) acc[i] = (f32x4){0.f, 0.f, 0.f, 0.f};

#pragma unroll
    for (int kb = 0; kb < 4; ++kb) {
        const int koff = kb * 32 + quad * 8;
        bf16x8 a = *(const bf16x8*)(sA + (wv * 16 + qm) * 136 + koff);
#pragma unroll
        for (int n0 = 0; n0 < 8; ++n0) {
            bf16x8 b = *(const bf16x8*)(p.Wt2 + (n0 * 16 + qm) * 128 + koff);
            acc[n0] = __builtin_amdgcn_mfma_f32_16x16x32_bf16(a, b, acc[n0], 0, 0, 0);
        }
    }

#pragma unroll
    for (int n0 = 0; n0 < 8; ++n0)
#pragma unroll
        for (int r = 0; r < 4; ++r)
            sE[(wv * 16 + quad * 4 + r) * 136 + n0 * 16 + qm] = f2bf(acc[n0][r]);
    __syncthreads();

    const int row_in = lane >> 2;
    const int c0 = (lane & 3) * 4;
    const int grow = row0 + wv * 16 + row_in;
    if (grow < p.N) {
#pragma unroll
        for (int j = 0; j < 4; ++j)
            *(int4*)(p.H2 + (size_t)grow * 128 + (c0 + j) * 8) =
                *(const int4*)(&sE[(wv * 16 + row_in) * 136 + (c0 + j) * 8]);
    }
}
__global__ __launch_bounds__(256) void k_a5(Params p) {      // gather2 -> out fp32
    gather2_body(p, (const ushort4*)p.H2, (const float4*)p.b2, (float4*)p.out, blockIdx.x);
}

extern "C" void kernel_launch(void* const* d_in, const int* in_sizes, int n_in,
                              void* d_out, int out_size, void* d_ws, size_t ws_size,
                              hipStream_t stream) {
    Params p;
    p.x  = (const float*)d_in[0];
    p.ei = (const int*)d_in[1];
    p.ew = (const float*)d_in[2];
    p.W1 = (const float*)d_in[3];
    p.b1 = (const float*)d_in[4];
    p.W2 = (const float*)d_in[5];
    p.b2 = (const float*)d_in[6];
    p.out = (float*)d_out;

    p.N = in_sizes[0] / D;
    p.E = in_sizes[2];
    p.C = (p.N + CSZ - 1) / CSZ;
    p.B2n = (p.E + EPB2 - 1) / EPB2;
    p.gb = (p.N + 63) / 64;
    p.hb = (p.N + 7) / 8;

    char* w = (char*)d_ws;
    auto alloc = [&](size_t bytes) {
        void* r = (void*)w;
        w += (bytes + 255) & ~(size_t)255;
        return r;
    };
    p.ctot     = (unsigned int*)alloc((size_t)p.C * 4);
    p.cbase    = (int*)alloc((size_t)(p.C + 1) * 4);
    p.gcur     = (unsigned int*)alloc((size_t)p.C * 4);
    p.dinv     = (float*)alloc((size_t)p.N * 4);
    p.cnt      = (int*)alloc((size_t)p.N * 4);
    p.rowstart = (int*)alloc((size_t)p.N * 4);
    p.brec     = (int2*)alloc((size_t)p.E * 8);
    p.erec     = (int2*)alloc((size_t)p.E * 8);
    p.Hbuf     = (unsigned short*)alloc((size_t)p.N * D * 2);
    p.H2       = (unsigned short*)alloc((size_t)p.N * D * 2);
    p.Wt1      = (unsigned short*)alloc(128 * 128 * 2);
    p.Wt2      = (unsigned short*)alloc(128 * 128 * 2);

    hipMemsetAsync(p.ctot, 0, (size_t)p.C * 4, stream);
    k_a0<<<2 + p.B2n, 256, 0, stream>>>(p);
    k_a1<<<p.gb + 1, 256, 0, stream>>>(p);
    k_a2<<<p.B2n, 256, 0, stream>>>(p);
    k_a3<<<p.C, 256, 0, stream>>>(p);
    k_a4<<<p.gb, 256, 0, stream>>>(p);
    k_a5<<<p.hb, 256, 0, stream>>>(p);
}